// Round 11
// baseline (463.823 us; speedup 1.0000x reference)
//
#include <hip/hip_runtime.h>
#include <math.h>

#define NF   529
#define K9   2304
#define NP   544
#define DMAP 45

typedef unsigned short ush;
typedef unsigned int u32;
typedef __bf16 bf8_t __attribute__((ext_vector_type(8)));
typedef float f4_t __attribute__((ext_vector_type(4)));
typedef ush ush8 __attribute__((ext_vector_type(8)));

// Interleaved split layout: tensor[row][K/32][plane(hi,lo)][32] ush. Row stride 2*K.

__device__ __forceinline__ ush f2bf(float f) {
  union { float f; u32 u; } v; v.f = f;
  u32 r = v.u + 0x7fffu + ((v.u >> 16) & 1u);
  return (ush)(r >> 16);
}
__device__ __forceinline__ float bf2f(ush h) {
  union { u32 u; float f; } v; v.u = ((u32)h) << 16;
  return v.f;
}
__device__ __forceinline__ void async16(const void* g, void* l) {
  __builtin_amdgcn_global_load_lds((const __attribute__((address_space(1))) u32*)g,
                                   (__attribute__((address_space(3))) u32*)l, 16, 0, 0);
}

// ---- PREP (one dispatch): filter->hi/lo split | im2col+pack | maps + zero numden ----
// Block ranges are uniform-branch: [0,4761) convert, [4761,7641) im2col, [7641,7650) tail.
// The fp32 F copy is GONE: iter-0 consumers (fgrad reg*F, epi3_update base) read filt
// directly — identical values, so results are bit-identical.
__global__ void prep(const float* __restrict__ filt, ush* __restrict__ Fhl,
                     const float* __restrict__ feat,
                     ush* __restrict__ Xbhl, ush* __restrict__ XThl,
                     const float* __restrict__ wl, const float* __restrict__ wsp,
                     float* __restrict__ labelF, float* __restrict__ spatialF,
                     float* __restrict__ numden) {
  __shared__ float T[64][65];
  const int b = blockIdx.x;
  const int t = threadIdx.x;

  if (b < 4761) {                               // ---- convert_f (no F copy) ----
    int g = b * 256 + t;
    int row = g / 288;
    int kk = (g - row * 288) * 8;
    int s = row / NF, m = row - s * NF;
    const float4* fp = (const float4*)(filt + (size_t)row * K9 + kk);
    float4 a = fp[0], bb = fp[1];
    float vv[8] = {a.x, a.y, a.z, a.w, bb.x, bb.y, bb.z, bb.w};
    ush8 h, lo;
#pragma unroll
    for (int i = 0; i < 8; ++i) {
      ush hh = f2bf(vv[i]);
      h[i] = hh;
      lo[i] = f2bf(vv[i] - bf2f(hh));
    }
    size_t o = ((size_t)s * 576 + m) * (2 * K9) + (kk >> 5) * 64 + (kk & 31);
    *(ush8*)(Fhl + o) = h;
    *(ush8*)(Fhl + o + 32) = lo;
    return;
  }

  if (b < 4761 + 2880) {                        // ---- im2col_pack ----
    int b2 = b - 4761;
    int s = b2 / 360, rem = b2 - s * 360;
    int k0 = (rem / 10) * 64, yx0 = (rem - (rem / 10) * 10) * 64;
    int r = t >> 2, c4 = (t & 3) * 16;
    int k = k0 + r;
    int ck = k / 9, j = k - ck * 9;
    int dy = j / 3 - 1, dx = j - (j / 3) * 3 - 1;
    const float* fb = feat + ((size_t)s * 256 + ck) * 529;
    float v[16];
#pragma unroll
    for (int i = 0; i < 16; ++i) {
      int yx = yx0 + c4 + i;
      float vv = 0.f;
      if (yx < NF) {
        int yy = yx / 23;
        int y = yy + dy, x = yx - yy * 23 + dx;
        if (y >= 0 && y < 23 && x >= 0 && x < 23) vv = fb[y * 23 + x];
      }
      v[i] = vv;
      T[r][c4 + i] = vv;
    }
    int c0 = yx0 + c4;
    if (c0 < NP) {
      size_t o = ((size_t)s * K9 + k) * (2 * NP) + (c0 >> 5) * 64 + (c0 & 31);
      ush8 h[2], lo[2];
#pragma unroll
      for (int gg = 0; gg < 2; ++gg)
#pragma unroll
        for (int i = 0; i < 8; ++i) {
          float vv = v[gg * 8 + i];
          ush hh = f2bf(vv);
          h[gg][i] = hh;
          lo[gg][i] = f2bf(vv - bf2f(hh));
        }
      *(ush8*)(Xbhl + o) = h[0];
      *(ush8*)(Xbhl + o + 8) = h[1];
      *(ush8*)(Xbhl + o + 32) = lo[0];
      *(ush8*)(Xbhl + o + 40) = lo[1];
    }
    __syncthreads();
    int kc = k0 + c4;
    size_t o2 = ((size_t)s * 640 + yx0 + r) * (2 * K9) + (kc >> 5) * 64 + (kc & 31);
    ush8 h2[2], l2[2];
#pragma unroll
    for (int gg = 0; gg < 2; ++gg)
#pragma unroll
      for (int i = 0; i < 8; ++i) {
        float vv = T[c4 + gg * 8 + i][r];
        ush hh = f2bf(vv);
        h2[gg][i] = hh;
        l2[gg][i] = f2bf(vv - bf2f(hh));
      }
    *(ush8*)(XThl + o2) = h2[0];
    *(ush8*)(XThl + o2 + 8) = h2[1];
    *(ush8*)(XThl + o2 + 32) = l2[0];
    *(ush8*)(XThl + o2 + 40) = l2[1];
    return;
  }

  // ---- tail: build maps + zero num/den accumulators ----
  int idx = (b - 7641) * 256 + t;
  for (int i = idx; i < 4 * 4240; i += 9 * 256) numden[i] = 0.f;
  if (idx < DMAP * DMAP) {
    int h = idx / DMAP, w = idx % DMAP;
    float dy = (float)(h - 22), dx = (float)(w - 22);
    float dist = sqrtf(dy * dy + dx * dx);
    float lab = 0.f, sp = 0.f;
#pragma unroll
    for (int bb = 0; bb < 9; ++bb) {
      float bd = dist * 2.f - (float)bb;
      float wt = fmaxf(0.f, 1.f - fabsf(bd));
      lab += wl[bb] * wt;
      sp  += wsp[bb] * wt;
    }
    float bd = dist * 2.f - 9.f;
    float wt = fminf(fmaxf(1.f + bd, 0.f), 1.f);
    lab += wl[9] * wt;
    sp  += wsp[9] * wt;
    labelF[idx] = lab;
    spatialF[idx] = sp;
  }
}

// ------------- MFMA GEMM, 128x64 tile, SINGLE-buffer LDS, XOR-swizzled banks -------------
// R7/R9's proven kernel, VERBATIM (R8's tail/wact gating regressed 2.4x — do not touch
// the staging/read/MFMA structure). barrier -> ds_read -> barrier -> stage(ch+1) -> MFMA.
// MODE=0: fp32 partials Cp[sk*8+s][640][640] via NONTEMPORAL stores (no L2 pollution).
// MODE=2: filter_grad epilogue (+reg*F -> FGhl split, num atomicAdd) — cached stores.
template <int KTOT, int ASPL, int BSPL, int MODE, int SKC, int CH, int BPG, int GX>
__launch_bounds__(256, 6)
__global__ void gemm128(const ush* __restrict__ Ahl, const ush* __restrict__ Bhl,
                        float* __restrict__ Cp,
                        const float* __restrict__ F, const float* __restrict__ frp,
                        ush* __restrict__ FGhl, float* __restrict__ numb,
                        const int arows) {
  __shared__ ush As[ASPL][128 * 32];
  __shared__ ush Bs[BSPL][64 * 32];

  const int tid = threadIdx.x;
  const int w = tid >> 6, l = tid & 63;
  const int wm = w & 1, wn = w >> 1;            // wn in {0,1}: 32-col halves
  const int q = l >> 4, c = l & 15;

  const int xcd = blockIdx.x & 7;
  const int t = blockIdx.x >> 3;
  const int g = xcd + 8 * (t / BPG);
  const int j = t % BPG;
  const int s = g / SKC, sk = g % SKC;
  const int x = j % GX, y = j / GX;
  const int m0 = x * 128, n0 = y * 64;

  const ush* A0 = Ahl + (size_t)s * arows * (2 * KTOT);
  const ush* B0 = Bhl + (size_t)s * ((MODE == 2) ? K9 : 640) * (2 * KTOT);

  // A staging: 256 threads cover 64 rows/iter (2 iters). B staging: 64 rows in one shot.
  const int srow = w * 16 + (l >> 2);           // 0..63
  const int scol = (l & 3) * 8;                 // LDS slot (fixed by DMA)
  const int ssw  = ((((l & 3) - (l >> 3)) & 3)) * 8;  // swizzled global seg
  const int rb   = tid >> 2;                    // 0..63 (B row)
  const int sb   = (tid & 3) * 8;
  const int sswb = (((tid & 3) - (tid >> 3)) & 3) * 8;

  auto stage = [&](int ch) {
    const int k2 = (sk * CH + ch) * 64;
#pragma unroll
    for (int i = 0; i < 2; ++i) {
      size_t ro = (size_t)(m0 + i * 64 + srow) * (2 * KTOT) + k2 + ssw;
      async16(A0 + ro, &As[0][(i * 64 + srow) * 32 + scol]);
      if (ASPL == 2) async16(A0 + ro + 32, &As[1][(i * 64 + srow) * 32 + scol]);
    }
    {
      size_t ro = (size_t)(n0 + rb) * (2 * KTOT) + k2 + sswb;
      async16(B0 + ro, &Bs[0][rb * 32 + sb]);
      if (BSPL == 2) async16(B0 + ro + 32, &Bs[1][rb * 32 + sb]);
    }
  };

  f4_t acc[4][2];
#pragma unroll
  for (int i = 0; i < 4; ++i)
#pragma unroll
    for (int jj = 0; jj < 2; ++jj) acc[i][jj] = (f4_t){0.f, 0.f, 0.f, 0.f};

  const int slotA = (((q + (c >> 1)) & 3)) * 8;

  stage(0);                                     // prologue prefetch

  for (int ch = 0; ch < CH; ++ch) {
    __syncthreads();                            // drain chunk ch's DMA batch

    bf8_t av[ASPL][4], bv[BSPL][2];
#pragma unroll
    for (int pp = 0; pp < ASPL; ++pp)
#pragma unroll
      for (int ti = 0; ti < 4; ++ti)
        av[pp][ti] = *(const bf8_t*)&As[pp][(wm * 64 + ti * 16 + c) * 32 + slotA];
#pragma unroll
    for (int pp = 0; pp < BSPL; ++pp)
#pragma unroll
      for (int tj = 0; tj < 2; ++tj)
        bv[pp][tj] = *(const bf8_t*)&Bs[pp][(wn * 32 + tj * 16 + c) * 32 + slotA];

    __syncthreads();                            // all waves done reading -> buffer dead
    if (ch + 1 < CH) stage(ch + 1);             // prefetch next chunk under the MFMAs

#pragma unroll
    for (int ti = 0; ti < 4; ++ti)
#pragma unroll
      for (int tj = 0; tj < 2; ++tj) {
        acc[ti][tj] = __builtin_amdgcn_mfma_f32_16x16x32_bf16(av[0][ti], bv[0][tj], acc[ti][tj], 0, 0, 0);
        if (ASPL == 2)
          acc[ti][tj] = __builtin_amdgcn_mfma_f32_16x16x32_bf16(av[1][ti], bv[0][tj], acc[ti][tj], 0, 0, 0);
        if (BSPL == 2)
          acc[ti][tj] = __builtin_amdgcn_mfma_f32_16x16x32_bf16(av[0][ti], bv[1][tj], acc[ti][tj], 0, 0, 0);
      }
  }

  if (MODE == 0) {
    float* C = Cp + (size_t)(sk * 8 + s) * 640 * 640;
#pragma unroll
    for (int ti = 0; ti < 4; ++ti)
#pragma unroll
      for (int tj = 0; tj < 2; ++tj)
#pragma unroll
        for (int r = 0; r < 4; ++r) {
          int m = m0 + wm * 64 + ti * 16 + q * 4 + r;
          int n = n0 + wn * 32 + tj * 16 + c;
          __builtin_nontemporal_store(acc[ti][tj][r], &C[(size_t)m * 640 + n]);
        }
  } else {
    float reg = fmaxf(frp[0] * frp[0], 1e-10f);
#pragma unroll
    for (int ti = 0; ti < 4; ++ti) {
      float ps[4] = {0.f, 0.f, 0.f, 0.f};
      int mb = m0 + wm * 64 + ti * 16 + q * 4;
#pragma unroll
      for (int tj = 0; tj < 2; ++tj) {
        int n = n0 + wn * 32 + tj * 16 + c;
#pragma unroll
        for (int r = 0; r < 4; ++r) {
          int m = mb + r;
          if (m < NF) {
            float v = acc[ti][tj][r] + reg * F[((size_t)s * NF + m) * K9 + n];
            size_t o = ((size_t)s * 576 + m) * (2 * K9) + ((n >> 5) * 64) + (n & 31);
            ush h = f2bf(v);
            FGhl[o] = h;
            FGhl[o + 32] = f2bf(v - bf2f(h));
            ps[r] += v * v;
          }
        }
      }
#pragma unroll
      for (int r = 0; r < 4; ++r) {
        float pp = ps[r];
        pp += __shfl_xor(pp, 1); pp += __shfl_xor(pp, 2);
        pp += __shfl_xor(pp, 4); pp += __shfl_xor(pp, 8);
        if (c == 0 && (mb + r) < NF) atomicAdd(&numb[s * NF + mb + r], pp);
      }
    }
  }
}

// ---- reduce partials (SK=2) + scores epilogue -> Rbhl, Mb; save raw scores S ----
__global__ void reduce_epi1(const float* __restrict__ Cp,
                            const float* __restrict__ labelF, const float* __restrict__ spatialF,
                            ush* __restrict__ Rbhl, ush* __restrict__ Mb,
                            float* __restrict__ Sv) {
  int row = blockIdx.x;             // 8*529
  int s = row / NF, m = row - s * NF;
  int a = m / 23, b = m - a * 23;
  const size_t sp = (size_t)8 * 640 * 640;
  const float* C = Cp + ((size_t)s * 640 + m) * 640;
  for (int n = threadIdx.x; n < NF; n += 256) {
    float v = __builtin_nontemporal_load(&C[n]) +
              __builtin_nontemporal_load(&C[sp + n]);
    Sv[(size_t)row * 544 + n] = v;
    int yy = n / 23, xx = n - yy * 23;
    int idx = (22 + yy - a) * DMAP + (22 + xx - b);
    float sw = spatialF[idx], lm = labelF[idx];
    float sa, msk;
    if (m == n) { sa = v; msk = 1.f; }
    else {
      sa = 0.5f * fabsf(v) + 0.5f * v;
      msk = (v > 0.f) ? 1.f : ((v < 0.f) ? 0.f : 0.5f);
    }
    float rv = msk * sw * sw * (sa - lm);
    size_t o = ((size_t)s * 640 + m) * (2 * NP) + ((n >> 5) * 64) + (n & 31);
    ush h = f2bf(rv);
    Rbhl[o] = h;
    Rbhl[o + 32] = f2bf(rv - bf2f(h));
    Mb[((size_t)s * NF + m) * NP + n] = f2bf(msk);
  }
}

// ---- FUSED: den row-sum (epi3) + filter update, one block per row ----
// Fin is the filter BASE to update from (iter0: the original filt input; iter1: F).
// F-row update FLOPs identical to the original update_f -> bit-identical output.
// Optionally saves raw G (iter 0, for scores2) and denb (read by scores2_fused).
__global__ void epi3_update(const float* __restrict__ Cp,
                            const float* __restrict__ spatialF, const ush* __restrict__ Mb,
                            const float* __restrict__ numb, const ush* __restrict__ FGhl,
                            const float* __restrict__ lsp, const float* __restrict__ frp,
                            const float* __restrict__ Fin, float* __restrict__ F,
                            float* __restrict__ denb, float* __restrict__ Gv) {
  int row = blockIdx.x;             // 8*529
  int s = row / NF, m = row - s * NF;
  int a = m / 23, b = m - a * 23;
  const size_t sp = (size_t)8 * 640 * 640;
  const float* C = Cp + ((size_t)s * 640 + m) * 640;
  float ss = 0.f;
  for (int n = threadIdx.x; n < NF; n += 256) {
    float v = __builtin_nontemporal_load(&C[n]) +
              __builtin_nontemporal_load(&C[sp + n]);
    if (Gv) Gv[(size_t)row * 544 + n] = v;
    int yy = n / 23, xx = n - yy * 23;
    int idx = (22 + yy - a) * DMAP + (22 + xx - b);
    float sw = spatialF[idx];
    float msk = bf2f(Mb[((size_t)s * NF + m) * NP + n]);
    float z = sw * msk * v;
    ss += z * z;
  }
  __shared__ float red[256];
  red[threadIdx.x] = ss; __syncthreads();
  for (int st = 128; st > 0; st >>= 1) {
    if (threadIdx.x < st) red[threadIdx.x] += red[threadIdx.x + st];
    __syncthreads();
  }
  float dn = red[0];
  if (threadIdx.x == 0) denb[row] = dn;
  float nm = numb[row];
  float reg = fmaxf(frp[0] * frp[0], 1e-10f);
  float alpha = nm / fmaxf(dn + reg * nm, 1e-8f);
  float sa = expf(lsp[0]) * alpha;
  size_t rbase = ((size_t)s * 576 + m) * (2 * K9);
  const float* Fr = Fin + (size_t)row * K9;
  float* Fo = F + (size_t)row * K9;
  for (int gI = threadIdx.x; gI < 288; gI += 256) {
    int kk = gI * 8;
    size_t o = rbase + (kk >> 5) * 64 + (kk & 31);
    ush8 gh = *(const ush8*)(FGhl + o);
    ush8 gl = *(const ush8*)(FGhl + o + 32);
    const float4* Fi = (const float4*)(Fr + kk);
    float4 aa = Fi[0], bb = Fi[1];
    float f[8] = {aa.x, aa.y, aa.z, aa.w, bb.x, bb.y, bb.z, bb.w};
#pragma unroll
    for (int i = 0; i < 8; ++i) f[i] -= sa * (bf2f(gh[i]) + bf2f(gl[i]));
    float4* Fp = (float4*)(Fo + kk);
    Fp[0] = (float4){f[0], f[1], f[2], f[3]};
    Fp[1] = (float4){f[4], f[5], f[6], f[7]};
  }
}

// ---- iter-2 scores WITHOUT a GEMM: scores2 = S - sa_m * G (conv linearity), + epi1 ----
// f1 = f0 - sa*FG exactly in fp32, conv linear in filter => scores2 = S - sa*G with the
// SAME product scheme. sa_m recomputed bit-identically from iter-0 num/den. (Validated
// R8/R9/R10: absmax 2.441e-4.)
__global__ void scores2_fused(const float* __restrict__ Sv, const float* __restrict__ Gv,
                              const float* __restrict__ numb, const float* __restrict__ denb,
                              const float* __restrict__ lsp, const float* __restrict__ frp,
                              const float* __restrict__ labelF, const float* __restrict__ spatialF,
                              ush* __restrict__ Rbhl, ush* __restrict__ Mb) {
  int row = blockIdx.x;             // 8*529
  int s = row / NF, m = row - s * NF;
  int a = m / 23, b = m - a * 23;
  float reg = fmaxf(frp[0] * frp[0], 1e-10f);
  float nm = numb[row], dn = denb[row];
  float alpha = nm / fmaxf(dn + reg * nm, 1e-8f);
  float sa2 = expf(lsp[0]) * alpha;
  const float* S = Sv + (size_t)row * 544;
  const float* G = Gv + (size_t)row * 544;
  for (int n = threadIdx.x; n < NF; n += 256) {
    float v = S[n] - sa2 * G[n];
    int yy = n / 23, xx = n - yy * 23;
    int idx = (22 + yy - a) * DMAP + (22 + xx - b);
    float sw = spatialF[idx], lm = labelF[idx];
    float sa, msk;
    if (m == n) { sa = v; msk = 1.f; }
    else {
      sa = 0.5f * fabsf(v) + 0.5f * v;
      msk = (v > 0.f) ? 1.f : ((v < 0.f) ? 0.f : 0.5f);
    }
    float rv = msk * sw * sw * (sa - lm);
    size_t o = ((size_t)s * 640 + m) * (2 * NP) + ((n >> 5) * 64) + (n & 31);
    ush h = f2bf(rv);
    Rbhl[o] = h;
    Rbhl[o + 32] = f2bf(rv - bf2f(h));
    Mb[((size_t)s * NF + m) * NP + n] = f2bf(msk);
  }
}

// ---------------- driver ----------------
extern "C" void kernel_launch(void* const* d_in, const int* in_sizes, int n_in,
                              void* d_out, int out_size, void* d_ws, size_t ws_size,
                              hipStream_t stream) {
  const float* filt = (const float*)d_in[0];
  const float* feat = (const float*)d_in[1];
  const float* wl   = (const float*)d_in[2];
  const float* wsp  = (const float*)d_in[3];
  const float* lsp  = (const float*)d_in[4];
  const float* frp  = (const float*)d_in[5];
  float* F = (float*)d_out;

  float* fb       = (float*)d_ws;
  float* labelF   = fb;
  float* spatialF = fb + 2048;
  float* numden   = fb + 4096;             // [2 iters][num|den][4240]
  ush* cur = (ush*)(fb + 4096 + 4 * 4240);

  const size_t szF  = (size_t)8 * 576 * (2 * K9);   // 21,233,664
  const size_t szXT = (size_t)8 * 640 * (2 * K9);   // 23,592,960
  const size_t szXb = (size_t)8 * K9 * (2 * NP);    // 20,054,016
  const size_t szRb = (size_t)8 * 640 * (2 * NP);   //  5,570,560
  const size_t szMb = (size_t)8 * NF * NP;          //  2,302,208
  const size_t szSv = (size_t)8 * NF * 544;         //  2,302,208 floats

  // Order matters: Fhl and FGhl are A-operands whose 128-row tiles overrun by
  // up to 63 rows for the last sample — the following tensor absorbs the
  // (discarded) reads. Cp (exact-sized) goes last.
  ush* Fhl  = cur;           cur += szF;
  ush* FGhl = cur;           cur += szF;
  ush* XThl = cur;           cur += szXT;
  ush* Xbhl = cur;           cur += szXb;
  ush* Rbhl = cur;           cur += szRb;
  ush* Mb   = cur;           cur += szMb;
  float* Sb = (float*)cur;   cur += szSv * 2;       // raw iter-0 scores, [row][544] f32
  float* Gb = (float*)cur;   cur += szSv * 2;       // raw iter-0 FG*X^T,  [row][544] f32
  float* Cp = (float*)((((size_t)cur) + 15) & ~(size_t)15);
  // Cp: 2*8*640*640 fp32 = 26.2 MB (SK=2)

  // One prep dispatch: convert (no F copy) + im2col + maps + numden zero.
  prep<<<7650, 256, 0, stream>>>(filt, Fhl, feat, Xbhl, XThl, wl, wsp,
                                 labelF, spatialF, numden);

  float* numb0 = numden;
  float* denb0 = numden + 4240;
  float* numb1 = numden + 2 * 4240;
  float* denb1 = numden + 3 * 4240;

  // ---------------- iteration 0 ----------------
  // scores partials (3-product split bf16), SK=2, 128x64, 9 N-tiles -> Cp (NT stores)
  gemm128<K9, 2, 2, 0, 2, 36, 45, 5><<<720, 256, 0, stream>>>(
      Fhl, XThl, Cp, nullptr, nullptr, nullptr, nullptr, 576);
  reduce_epi1<<<8 * NF, 256, 0, stream>>>(Cp, labelF, spatialF, Rbhl, Mb, Sb);
  // filter_grad = R*X^T + reg*f0 (3-product), K=544 -> FGhl + num (f0 = filt directly)
  gemm128<NP, 2, 2, 2, 1, 17, 180, 5><<<1440, 256, 0, stream>>>(
      Rbhl, Xbhl, nullptr, filt, frp, FGhl, numb0, 640);
  // scores_grad partials — 3-PRODUCT (G feeds scores2 directly), SK=2 -> Cp
  gemm128<K9, 2, 2, 0, 2, 36, 45, 5><<<720, 256, 0, stream>>>(
      FGhl, XThl, Cp, nullptr, nullptr, nullptr, nullptr, 576);
  // fused: den0 + F update from base=filt (first write of F); saves G
  epi3_update<<<8 * NF, 256, 0, stream>>>(Cp, spatialF, Mb, numb0, FGhl, lsp, frp,
                                          filt, F, denb0, Gb);

  // ---------------- iteration 1 ----------------
  // scores2 = S - sa*G (no GEMM) + epi1 epilogue
  scores2_fused<<<8 * NF, 256, 0, stream>>>(Sb, Gb, numb0, denb0, lsp, frp,
                                            labelF, spatialF, Rbhl, Mb);
  gemm128<NP, 2, 2, 2, 1, 17, 180, 5><<<1440, 256, 0, stream>>>(
      Rbhl, Xbhl, nullptr, F, frp, FGhl, numb1, 640);
  // scores_grad partials (1-product: only feeds den2), SK=2 -> Cp
  gemm128<K9, 1, 1, 0, 2, 36, 45, 5><<<720, 256, 0, stream>>>(
      FGhl, XThl, Cp, nullptr, nullptr, nullptr, nullptr, 576);
  // fused: den1 + final F update (base=F)
  epi3_update<<<8 * NF, 256, 0, stream>>>(Cp, spatialF, Mb, numb1, FGhl, lsp, frp,
                                          F, F, denb1, nullptr);
}

// Round 12
// 450.596 us; speedup vs baseline: 1.0294x; 1.0294x over previous
//
#include <hip/hip_runtime.h>
#include <math.h>

#define NF   529
#define K9   2304
#define NP   544
#define DMAP 45

typedef unsigned short ush;
typedef unsigned int u32;
typedef __bf16 bf8_t __attribute__((ext_vector_type(8)));
typedef float f4_t __attribute__((ext_vector_type(4)));
typedef ush ush8 __attribute__((ext_vector_type(8)));

// Interleaved split layout: tensor[row][K/32][plane(hi,lo)][32] ush. Row stride 2*K.

__device__ __forceinline__ ush f2bf(float f) {
  union { float f; u32 u; } v; v.f = f;
  u32 r = v.u + 0x7fffu + ((v.u >> 16) & 1u);
  return (ush)(r >> 16);
}
__device__ __forceinline__ float bf2f(ush h) {
  union { u32 u; float f; } v; v.u = ((u32)h) << 16;
  return v.f;
}
__device__ __forceinline__ void async16(const void* g, void* l) {
  __builtin_amdgcn_global_load_lds((const __attribute__((address_space(1))) u32*)g,
                                   (__attribute__((address_space(3))) u32*)l, 16, 0, 0);
}

// ---- PREP (one dispatch): filter->hi/lo split | im2col+pack | maps + zero numden ----
// Block ranges are uniform-branch: [0,4761) convert, [4761,7641) im2col, [7641,7650) tail.
// No fp32 F copy: iter-0 consumers (fgrad reg*F, epi3_update base) read filt directly.
__global__ void prep(const float* __restrict__ filt, ush* __restrict__ Fhl,
                     const float* __restrict__ feat,
                     ush* __restrict__ Xbhl, ush* __restrict__ XThl,
                     const float* __restrict__ wl, const float* __restrict__ wsp,
                     float* __restrict__ labelF, float* __restrict__ spatialF,
                     float* __restrict__ numden) {
  __shared__ float T[64][65];
  const int b = blockIdx.x;
  const int t = threadIdx.x;

  if (b < 4761) {                               // ---- convert_f (no F copy) ----
    int g = b * 256 + t;
    int row = g / 288;
    int kk = (g - row * 288) * 8;
    int s = row / NF, m = row - s * NF;
    const float4* fp = (const float4*)(filt + (size_t)row * K9 + kk);
    float4 a = fp[0], bb = fp[1];
    float vv[8] = {a.x, a.y, a.z, a.w, bb.x, bb.y, bb.z, bb.w};
    ush8 h, lo;
#pragma unroll
    for (int i = 0; i < 8; ++i) {
      ush hh = f2bf(vv[i]);
      h[i] = hh;
      lo[i] = f2bf(vv[i] - bf2f(hh));
    }
    size_t o = ((size_t)s * 576 + m) * (2 * K9) + (kk >> 5) * 64 + (kk & 31);
    *(ush8*)(Fhl + o) = h;
    *(ush8*)(Fhl + o + 32) = lo;
    return;
  }

  if (b < 4761 + 2880) {                        // ---- im2col_pack ----
    int b2 = b - 4761;
    int s = b2 / 360, rem = b2 - s * 360;
    int k0 = (rem / 10) * 64, yx0 = (rem - (rem / 10) * 10) * 64;
    int r = t >> 2, c4 = (t & 3) * 16;
    int k = k0 + r;
    int ck = k / 9, j = k - ck * 9;
    int dy = j / 3 - 1, dx = j - (j / 3) * 3 - 1;
    const float* fb = feat + ((size_t)s * 256 + ck) * 529;
    float v[16];
#pragma unroll
    for (int i = 0; i < 16; ++i) {
      int yx = yx0 + c4 + i;
      float vv = 0.f;
      if (yx < NF) {
        int yy = yx / 23;
        int y = yy + dy, x = yx - yy * 23 + dx;
        if (y >= 0 && y < 23 && x >= 0 && x < 23) vv = fb[y * 23 + x];
      }
      v[i] = vv;
      T[r][c4 + i] = vv;
    }
    int c0 = yx0 + c4;
    if (c0 < NP) {
      size_t o = ((size_t)s * K9 + k) * (2 * NP) + (c0 >> 5) * 64 + (c0 & 31);
      ush8 h[2], lo[2];
#pragma unroll
      for (int gg = 0; gg < 2; ++gg)
#pragma unroll
        for (int i = 0; i < 8; ++i) {
          float vv = v[gg * 8 + i];
          ush hh = f2bf(vv);
          h[gg][i] = hh;
          lo[gg][i] = f2bf(vv - bf2f(hh));
        }
      *(ush8*)(Xbhl + o) = h[0];
      *(ush8*)(Xbhl + o + 8) = h[1];
      *(ush8*)(Xbhl + o + 32) = lo[0];
      *(ush8*)(Xbhl + o + 40) = lo[1];
    }
    __syncthreads();
    int kc = k0 + c4;
    size_t o2 = ((size_t)s * 640 + yx0 + r) * (2 * K9) + (kc >> 5) * 64 + (kc & 31);
    ush8 h2[2], l2[2];
#pragma unroll
    for (int gg = 0; gg < 2; ++gg)
#pragma unroll
      for (int i = 0; i < 8; ++i) {
        float vv = T[c4 + gg * 8 + i][r];
        ush hh = f2bf(vv);
        h2[gg][i] = hh;
        l2[gg][i] = f2bf(vv - bf2f(hh));
      }
    *(ush8*)(XThl + o2) = h2[0];
    *(ush8*)(XThl + o2 + 8) = h2[1];
    *(ush8*)(XThl + o2 + 32) = l2[0];
    *(ush8*)(XThl + o2 + 40) = l2[1];
    return;
  }

  // ---- tail: build maps + zero num/den accumulators ----
  int idx = (b - 7641) * 256 + t;
  for (int i = idx; i < 4 * 4240; i += 9 * 256) numden[i] = 0.f;
  if (idx < DMAP * DMAP) {
    int h = idx / DMAP, w = idx % DMAP;
    float dy = (float)(h - 22), dx = (float)(w - 22);
    float dist = sqrtf(dy * dy + dx * dx);
    float lab = 0.f, sp = 0.f;
#pragma unroll
    for (int bb = 0; bb < 9; ++bb) {
      float bd = dist * 2.f - (float)bb;
      float wt = fmaxf(0.f, 1.f - fabsf(bd));
      lab += wl[bb] * wt;
      sp  += wsp[bb] * wt;
    }
    float bd = dist * 2.f - 9.f;
    float wt = fminf(fmaxf(1.f + bd, 0.f), 1.f);
    lab += wl[9] * wt;
    sp  += wsp[9] * wt;
    labelF[idx] = lab;
    spatialF[idx] = sp;
  }
}

// ------------- MFMA GEMM, 128x64 tile, SINGLE-buffer LDS, XOR-swizzled banks -------------
// R7/R9's proven kernel, VERBATIM (R8's tail/wact gating regressed 2.4x — do not touch
// the staging/read/MFMA structure). barrier -> ds_read -> barrier -> stage(ch+1) -> MFMA.
// MODE=0: fp32 partials Cp[sk*8+s][640][640] via NONTEMPORAL stores (no L2 pollution).
// MODE=2: filter_grad epilogue (+reg*F -> FGhl split, num atomicAdd) — cached stores.
template <int KTOT, int ASPL, int BSPL, int MODE, int SKC, int CH, int BPG, int GX>
__launch_bounds__(256, 6)
__global__ void gemm128(const ush* __restrict__ Ahl, const ush* __restrict__ Bhl,
                        float* __restrict__ Cp,
                        const float* __restrict__ F, const float* __restrict__ frp,
                        ush* __restrict__ FGhl, float* __restrict__ numb,
                        const int arows) {
  __shared__ ush As[ASPL][128 * 32];
  __shared__ ush Bs[BSPL][64 * 32];

  const int tid = threadIdx.x;
  const int w = tid >> 6, l = tid & 63;
  const int wm = w & 1, wn = w >> 1;            // wn in {0,1}: 32-col halves
  const int q = l >> 4, c = l & 15;

  const int xcd = blockIdx.x & 7;
  const int t = blockIdx.x >> 3;
  const int g = xcd + 8 * (t / BPG);
  const int j = t % BPG;
  const int s = g / SKC, sk = g % SKC;
  const int x = j % GX, y = j / GX;
  const int m0 = x * 128, n0 = y * 64;

  const ush* A0 = Ahl + (size_t)s * arows * (2 * KTOT);
  const ush* B0 = Bhl + (size_t)s * ((MODE == 2) ? K9 : 640) * (2 * KTOT);

  // A staging: 256 threads cover 64 rows/iter (2 iters). B staging: 64 rows in one shot.
  const int srow = w * 16 + (l >> 2);           // 0..63
  const int scol = (l & 3) * 8;                 // LDS slot (fixed by DMA)
  const int ssw  = ((((l & 3) - (l >> 3)) & 3)) * 8;  // swizzled global seg
  const int rb   = tid >> 2;                    // 0..63 (B row)
  const int sb   = (tid & 3) * 8;
  const int sswb = (((tid & 3) - (tid >> 3)) & 3) * 8;

  auto stage = [&](int ch) {
    const int k2 = (sk * CH + ch) * 64;
#pragma unroll
    for (int i = 0; i < 2; ++i) {
      size_t ro = (size_t)(m0 + i * 64 + srow) * (2 * KTOT) + k2 + ssw;
      async16(A0 + ro, &As[0][(i * 64 + srow) * 32 + scol]);
      if (ASPL == 2) async16(A0 + ro + 32, &As[1][(i * 64 + srow) * 32 + scol]);
    }
    {
      size_t ro = (size_t)(n0 + rb) * (2 * KTOT) + k2 + sswb;
      async16(B0 + ro, &Bs[0][rb * 32 + sb]);
      if (BSPL == 2) async16(B0 + ro + 32, &Bs[1][rb * 32 + sb]);
    }
  };

  f4_t acc[4][2];
#pragma unroll
  for (int i = 0; i < 4; ++i)
#pragma unroll
    for (int jj = 0; jj < 2; ++jj) acc[i][jj] = (f4_t){0.f, 0.f, 0.f, 0.f};

  const int slotA = (((q + (c >> 1)) & 3)) * 8;

  stage(0);                                     // prologue prefetch

  for (int ch = 0; ch < CH; ++ch) {
    __syncthreads();                            // drain chunk ch's DMA batch

    bf8_t av[ASPL][4], bv[BSPL][2];
#pragma unroll
    for (int pp = 0; pp < ASPL; ++pp)
#pragma unroll
      for (int ti = 0; ti < 4; ++ti)
        av[pp][ti] = *(const bf8_t*)&As[pp][(wm * 64 + ti * 16 + c) * 32 + slotA];
#pragma unroll
    for (int pp = 0; pp < BSPL; ++pp)
#pragma unroll
      for (int tj = 0; tj < 2; ++tj)
        bv[pp][tj] = *(const bf8_t*)&Bs[pp][(wn * 32 + tj * 16 + c) * 32 + slotA];

    __syncthreads();                            // all waves done reading -> buffer dead
    if (ch + 1 < CH) stage(ch + 1);             // prefetch next chunk under the MFMAs

#pragma unroll
    for (int ti = 0; ti < 4; ++ti)
#pragma unroll
      for (int tj = 0; tj < 2; ++tj) {
        acc[ti][tj] = __builtin_amdgcn_mfma_f32_16x16x32_bf16(av[0][ti], bv[0][tj], acc[ti][tj], 0, 0, 0);
        if (ASPL == 2)
          acc[ti][tj] = __builtin_amdgcn_mfma_f32_16x16x32_bf16(av[1][ti], bv[0][tj], acc[ti][tj], 0, 0, 0);
        if (BSPL == 2)
          acc[ti][tj] = __builtin_amdgcn_mfma_f32_16x16x32_bf16(av[0][ti], bv[1][tj], acc[ti][tj], 0, 0, 0);
      }
  }

  if (MODE == 0) {
    float* C = Cp + (size_t)(sk * 8 + s) * 640 * 640;
#pragma unroll
    for (int ti = 0; ti < 4; ++ti)
#pragma unroll
      for (int tj = 0; tj < 2; ++tj)
#pragma unroll
        for (int r = 0; r < 4; ++r) {
          int m = m0 + wm * 64 + ti * 16 + q * 4 + r;
          int n = n0 + wn * 32 + tj * 16 + c;
          __builtin_nontemporal_store(acc[ti][tj][r], &C[(size_t)m * 640 + n]);
        }
  } else {
    float reg = fmaxf(frp[0] * frp[0], 1e-10f);
#pragma unroll
    for (int ti = 0; ti < 4; ++ti) {
      float ps[4] = {0.f, 0.f, 0.f, 0.f};
      int mb = m0 + wm * 64 + ti * 16 + q * 4;
#pragma unroll
      for (int tj = 0; tj < 2; ++tj) {
        int n = n0 + wn * 32 + tj * 16 + c;
#pragma unroll
        for (int r = 0; r < 4; ++r) {
          int m = mb + r;
          if (m < NF) {
            float v = acc[ti][tj][r] + reg * F[((size_t)s * NF + m) * K9 + n];
            size_t o = ((size_t)s * 576 + m) * (2 * K9) + ((n >> 5) * 64) + (n & 31);
            ush h = f2bf(v);
            FGhl[o] = h;
            FGhl[o + 32] = f2bf(v - bf2f(h));
            ps[r] += v * v;
          }
        }
      }
#pragma unroll
      for (int r = 0; r < 4; ++r) {
        float pp = ps[r];
        pp += __shfl_xor(pp, 1); pp += __shfl_xor(pp, 2);
        pp += __shfl_xor(pp, 4); pp += __shfl_xor(pp, 8);
        if (c == 0 && (mb + r) < NF) atomicAdd(&numb[s * NF + mb + r], pp);
      }
    }
  }
}

// ---- reduce partials (SK=2) + scores epilogue -> Rbhl, Mb; save raw scores S ----
__global__ void reduce_epi1(const float* __restrict__ Cp,
                            const float* __restrict__ labelF, const float* __restrict__ spatialF,
                            ush* __restrict__ Rbhl, ush* __restrict__ Mb,
                            float* __restrict__ Sv) {
  int row = blockIdx.x;             // 8*529
  int s = row / NF, m = row - s * NF;
  int a = m / 23, b = m - a * 23;
  const size_t sp = (size_t)8 * 640 * 640;
  const float* C = Cp + ((size_t)s * 640 + m) * 640;
  for (int n = threadIdx.x; n < NF; n += 256) {
    float v = __builtin_nontemporal_load(&C[n]) +
              __builtin_nontemporal_load(&C[sp + n]);
    Sv[(size_t)row * 544 + n] = v;
    int yy = n / 23, xx = n - yy * 23;
    int idx = (22 + yy - a) * DMAP + (22 + xx - b);
    float sw = spatialF[idx], lm = labelF[idx];
    float sa, msk;
    if (m == n) { sa = v; msk = 1.f; }
    else {
      sa = 0.5f * fabsf(v) + 0.5f * v;
      msk = (v > 0.f) ? 1.f : ((v < 0.f) ? 0.f : 0.5f);
    }
    float rv = msk * sw * sw * (sa - lm);
    size_t o = ((size_t)s * 640 + m) * (2 * NP) + ((n >> 5) * 64) + (n & 31);
    ush h = f2bf(rv);
    Rbhl[o] = h;
    Rbhl[o + 32] = f2bf(rv - bf2f(h));
    Mb[((size_t)s * NF + m) * NP + n] = f2bf(msk);
  }
}

// ---- FUSED iter-0 tail: den0 row-sum + F update + scores2 epilogue, one block/row ----
// Pass 1 computes v = sum of Cp spans (the raw G row), caches it in LDS Grow[], and
// accumulates den with the iter-0 mask (read from Mb). After the tree reduction:
// alpha/sa identical formulas to update_f; F row updated from base Fin (=filt).
// Then scores2 = S - sa*Grow (conv linearity, validated R8-R11) overwrites Rbhl/Mb for
// iter 1. Mb read(pass1)->write(pass3) hazard cleared by the reduction barriers.
// Gb buffer eliminated entirely (the G row never leaves the block).
__global__ void epi3_upd_sc2(const float* __restrict__ Cp,
                             const float* __restrict__ spatialF, const float* __restrict__ labelF,
                             ush* __restrict__ Mb,
                             const float* __restrict__ numb, const ush* __restrict__ FGhl,
                             const float* __restrict__ lsp, const float* __restrict__ frp,
                             const float* __restrict__ Fin, float* __restrict__ F,
                             const float* __restrict__ Sv, ush* __restrict__ Rbhl) {
  __shared__ float red[256];
  __shared__ float Grow[NF];
  int row = blockIdx.x;             // 8*529
  int s = row / NF, m = row - s * NF;
  int a = m / 23, b = m - a * 23;
  const size_t sp = (size_t)8 * 640 * 640;
  const float* C = Cp + ((size_t)s * 640 + m) * 640;
  float ss = 0.f;
  for (int n = threadIdx.x; n < NF; n += 256) {
    float v = __builtin_nontemporal_load(&C[n]) +
              __builtin_nontemporal_load(&C[sp + n]);
    Grow[n] = v;
    int yy = n / 23, xx = n - yy * 23;
    int idx = (22 + yy - a) * DMAP + (22 + xx - b);
    float sw = spatialF[idx];
    float msk = bf2f(Mb[((size_t)s * NF + m) * NP + n]);
    float z = sw * msk * v;
    ss += z * z;
  }
  red[threadIdx.x] = ss; __syncthreads();
  for (int st = 128; st > 0; st >>= 1) {
    if (threadIdx.x < st) red[threadIdx.x] += red[threadIdx.x + st];
    __syncthreads();
  }
  float dn = red[0];
  float nm = numb[row];
  float reg = fmaxf(frp[0] * frp[0], 1e-10f);
  float alpha = nm / fmaxf(dn + reg * nm, 1e-8f);
  float sa = expf(lsp[0]) * alpha;
  // ---- F-row update (bit-identical to update_f) ----
  size_t rbase = ((size_t)s * 576 + m) * (2 * K9);
  const float* Fr = Fin + (size_t)row * K9;
  float* Fo = F + (size_t)row * K9;
  for (int gI = threadIdx.x; gI < 288; gI += 256) {
    int kk = gI * 8;
    size_t o = rbase + (kk >> 5) * 64 + (kk & 31);
    ush8 gh = *(const ush8*)(FGhl + o);
    ush8 gl = *(const ush8*)(FGhl + o + 32);
    const float4* Fi = (const float4*)(Fr + kk);
    float4 aa = Fi[0], bb = Fi[1];
    float f[8] = {aa.x, aa.y, aa.z, aa.w, bb.x, bb.y, bb.z, bb.w};
#pragma unroll
    for (int i = 0; i < 8; ++i) f[i] -= sa * (bf2f(gh[i]) + bf2f(gl[i]));
    float4* Fp = (float4*)(Fo + kk);
    Fp[0] = (float4){f[0], f[1], f[2], f[3]};
    Fp[1] = (float4){f[4], f[5], f[6], f[7]};
  }
  // ---- scores2 epilogue: v2 = S - sa*G, then epi1-identical masking -> Rbhl, Mb ----
  const float* S = Sv + (size_t)row * 544;
  for (int n = threadIdx.x; n < NF; n += 256) {
    float v = S[n] - sa * Grow[n];
    int yy = n / 23, xx = n - yy * 23;
    int idx = (22 + yy - a) * DMAP + (22 + xx - b);
    float sw = spatialF[idx], lm = labelF[idx];
    float sa2, msk;
    if (m == n) { sa2 = v; msk = 1.f; }
    else {
      sa2 = 0.5f * fabsf(v) + 0.5f * v;
      msk = (v > 0.f) ? 1.f : ((v < 0.f) ? 0.f : 0.5f);
    }
    float rv = msk * sw * sw * (sa2 - lm);
    size_t o = ((size_t)s * 640 + m) * (2 * NP) + ((n >> 5) * 64) + (n & 31);
    ush h = f2bf(rv);
    Rbhl[o] = h;
    Rbhl[o + 32] = f2bf(rv - bf2f(h));
    Mb[((size_t)s * NF + m) * NP + n] = f2bf(msk);
  }
}

// ---- FUSED iter-1 tail: den1 row-sum + final F update (no scores2) ----
__global__ void epi3_update(const float* __restrict__ Cp,
                            const float* __restrict__ spatialF, const ush* __restrict__ Mb,
                            const float* __restrict__ numb, const ush* __restrict__ FGhl,
                            const float* __restrict__ lsp, const float* __restrict__ frp,
                            const float* __restrict__ Fin, float* __restrict__ F) {
  int row = blockIdx.x;             // 8*529
  int s = row / NF, m = row - s * NF;
  int a = m / 23, b = m - a * 23;
  const size_t sp = (size_t)8 * 640 * 640;
  const float* C = Cp + ((size_t)s * 640 + m) * 640;
  float ss = 0.f;
  for (int n = threadIdx.x; n < NF; n += 256) {
    float v = __builtin_nontemporal_load(&C[n]) +
              __builtin_nontemporal_load(&C[sp + n]);
    int yy = n / 23, xx = n - yy * 23;
    int idx = (22 + yy - a) * DMAP + (22 + xx - b);
    float sw = spatialF[idx];
    float msk = bf2f(Mb[((size_t)s * NF + m) * NP + n]);
    float z = sw * msk * v;
    ss += z * z;
  }
  __shared__ float red[256];
  red[threadIdx.x] = ss; __syncthreads();
  for (int st = 128; st > 0; st >>= 1) {
    if (threadIdx.x < st) red[threadIdx.x] += red[threadIdx.x + st];
    __syncthreads();
  }
  float dn = red[0];
  float nm = numb[row];
  float reg = fmaxf(frp[0] * frp[0], 1e-10f);
  float alpha = nm / fmaxf(dn + reg * nm, 1e-8f);
  float sa = expf(lsp[0]) * alpha;
  size_t rbase = ((size_t)s * 576 + m) * (2 * K9);
  const float* Fr = Fin + (size_t)row * K9;
  float* Fo = F + (size_t)row * K9;
  for (int gI = threadIdx.x; gI < 288; gI += 256) {
    int kk = gI * 8;
    size_t o = rbase + (kk >> 5) * 64 + (kk & 31);
    ush8 gh = *(const ush8*)(FGhl + o);
    ush8 gl = *(const ush8*)(FGhl + o + 32);
    const float4* Fi = (const float4*)(Fr + kk);
    float4 aa = Fi[0], bb = Fi[1];
    float f[8] = {aa.x, aa.y, aa.z, aa.w, bb.x, bb.y, bb.z, bb.w};
#pragma unroll
    for (int i = 0; i < 8; ++i) f[i] -= sa * (bf2f(gh[i]) + bf2f(gl[i]));
    float4* Fp = (float4*)(Fo + kk);
    Fp[0] = (float4){f[0], f[1], f[2], f[3]};
    Fp[1] = (float4){f[4], f[5], f[6], f[7]};
  }
}

// ---------------- driver ----------------
extern "C" void kernel_launch(void* const* d_in, const int* in_sizes, int n_in,
                              void* d_out, int out_size, void* d_ws, size_t ws_size,
                              hipStream_t stream) {
  const float* filt = (const float*)d_in[0];
  const float* feat = (const float*)d_in[1];
  const float* wl   = (const float*)d_in[2];
  const float* wsp  = (const float*)d_in[3];
  const float* lsp  = (const float*)d_in[4];
  const float* frp  = (const float*)d_in[5];
  float* F = (float*)d_out;

  float* fb       = (float*)d_ws;
  float* labelF   = fb;
  float* spatialF = fb + 2048;
  float* numden   = fb + 4096;             // [2 iters][num|den][4240]
  ush* cur = (ush*)(fb + 4096 + 4 * 4240);

  const size_t szF  = (size_t)8 * 576 * (2 * K9);   // 21,233,664
  const size_t szXT = (size_t)8 * 640 * (2 * K9);   // 23,592,960
  const size_t szXb = (size_t)8 * K9 * (2 * NP);    // 20,054,016
  const size_t szRb = (size_t)8 * 640 * (2 * NP);   //  5,570,560
  const size_t szMb = (size_t)8 * NF * NP;          //  2,302,208
  const size_t szSv = (size_t)8 * NF * 544;         //  2,302,208 floats

  // Order matters: Fhl and FGhl are A-operands whose 128-row tiles overrun by
  // up to 63 rows for the last sample — the following tensor absorbs the
  // (discarded) reads. Cp (exact-sized) goes last.
  ush* Fhl  = cur;           cur += szF;
  ush* FGhl = cur;           cur += szF;
  ush* XThl = cur;           cur += szXT;
  ush* Xbhl = cur;           cur += szXb;
  ush* Rbhl = cur;           cur += szRb;
  ush* Mb   = cur;           cur += szMb;
  float* Sb = (float*)cur;   cur += szSv * 2;       // raw iter-0 scores, [row][544] f32
  float* Cp = (float*)((((size_t)cur) + 15) & ~(size_t)15);
  // Cp: 2*8*640*640 fp32 = 26.2 MB (SK=2)

  // One prep dispatch: convert (no F copy) + im2col + maps + numden zero.
  prep<<<7650, 256, 0, stream>>>(filt, Fhl, feat, Xbhl, XThl, wl, wsp,
                                 labelF, spatialF, numden);

  float* numb0 = numden;
  float* numb1 = numden + 2 * 4240;

  // ---------------- iteration 0 ----------------
  // scores partials (3-product split bf16), SK=2, 128x64, 9 N-tiles -> Cp (NT stores)
  gemm128<K9, 2, 2, 0, 2, 36, 45, 5><<<720, 256, 0, stream>>>(
      Fhl, XThl, Cp, nullptr, nullptr, nullptr, nullptr, 576);
  reduce_epi1<<<8 * NF, 256, 0, stream>>>(Cp, labelF, spatialF, Rbhl, Mb, Sb);
  // filter_grad = R*X^T + reg*f0 (3-product), K=544 -> FGhl + num (f0 = filt directly)
  gemm128<NP, 2, 2, 2, 1, 17, 180, 5><<<1440, 256, 0, stream>>>(
      Rbhl, Xbhl, nullptr, filt, frp, FGhl, numb0, 640);
  // scores_grad partials — 3-PRODUCT (G feeds scores2 directly), SK=2 -> Cp
  gemm128<K9, 2, 2, 0, 2, 36, 45, 5><<<720, 256, 0, stream>>>(
      FGhl, XThl, Cp, nullptr, nullptr, nullptr, nullptr, 576);
  // FUSED: den0 + F update (base=filt) + scores2 (= S - sa*G) -> Rbhl/Mb for iter 1
  epi3_upd_sc2<<<8 * NF, 256, 0, stream>>>(Cp, spatialF, labelF, Mb, numb0, FGhl,
                                           lsp, frp, filt, F, Sb, Rbhl);

  // ---------------- iteration 1 ----------------
  gemm128<NP, 2, 2, 2, 1, 17, 180, 5><<<1440, 256, 0, stream>>>(
      Rbhl, Xbhl, nullptr, F, frp, FGhl, numb1, 640);
  // scores_grad partials (1-product: only feeds den2), SK=2 -> Cp
  gemm128<K9, 1, 1, 0, 2, 36, 45, 5><<<720, 256, 0, stream>>>(
      FGhl, XThl, Cp, nullptr, nullptr, nullptr, nullptr, 576);
  // fused: den1 + final F update (base=F)
  epi3_update<<<8 * NF, 256, 0, stream>>>(Cp, spatialF, Mb, numb1, FGhl, lsp, frp,
                                          F, F);
}